// Round 11
// baseline (652.832 us; speedup 1.0000x reference)
//
#include <hip/hip_runtime.h>
#include <hip/hip_cooperative_groups.h>
#include <math.h>

namespace cg = cooperative_groups;

#define HID 1024
#define NROWS 2048

typedef __attribute__((ext_vector_type(8))) short short8;
typedef __attribute__((ext_vector_type(4))) short short4_t;
typedef __attribute__((ext_vector_type(4))) float f32x4;

__device__ __forceinline__ short f2bf(float f) {
  union { float f; unsigned u; } v; v.f = f;
  unsigned r = v.u + 0x7fffu + ((v.u >> 16) & 1u);
  return (short)(r >> 16);
}
__device__ __forceinline__ float bf2f(short s) {
  union { unsigned u; float f; } v; v.u = ((unsigned)(unsigned short)s) << 16;
  return v.f;
}
__device__ __forceinline__ float wave_sum(float a) {
#pragma unroll
  for (int off = 32; off; off >>= 1) a += __shfl_xor(a, off, 64);
  return a;
}

struct Params {
  const float* x; const int* y;
  const float *Wp0, *Wp1, *Wp2, *Wl0, *bl0, *Wl1, *bl1, *Wl2, *bl2, *Wc, *bc;
  short* xb;
  int *counts, *slot_of_row, *rows1, *rows2;
  short *WpT0, *WpT1, *WpT2, *WlT0, *WlT1, *WlT2;
  short *P0b, *P1c, *P2c;
  float *psh, *ps1, *ps2, *out;
};

// ---------------------------------------------------------------------------
// 32x32 transpose-convert tile (T = 32x33 fp32 LDS scratch).
// ---------------------------------------------------------------------------
__device__ __forceinline__ void transpose_tile(const float* __restrict__ W,
                                               short* __restrict__ BT,
                                               int K, int N, int Npad, int tn,
                                               int b, int tid, float* T) {
  __syncthreads();                      // guard LDS reuse across iterations
  const int n0 = (b % tn) * 32, k0 = (b / tn) * 32;
  const int r = tid >> 3, c = (tid & 7) * 4;
  float v0 = 0.f, v1 = 0.f, v2 = 0.f, v3 = 0.f;
  const float* p = &W[(size_t)(k0 + r) * N];
  if (n0 + c + 3 < N) {
    v0 = p[n0 + c]; v1 = p[n0 + c + 1]; v2 = p[n0 + c + 2]; v3 = p[n0 + c + 3];
  } else {
    if (n0 + c + 0 < N) v0 = p[n0 + c + 0];
    if (n0 + c + 1 < N) v1 = p[n0 + c + 1];
    if (n0 + c + 2 < N) v2 = p[n0 + c + 2];
  }
  T[r * 33 + c] = v0; T[r * 33 + c + 1] = v1;
  T[r * 33 + c + 2] = v2; T[r * 33 + c + 3] = v3;
  __syncthreads();
  const int nl = tid >> 3, kl = (tid & 7) * 4;
  const int n = n0 + nl;
  if (n < Npad) {
    short4_t o;
    o.x = (n < N) ? f2bf(T[(kl + 0) * 33 + nl]) : (short)0;
    o.y = (n < N) ? f2bf(T[(kl + 1) * 33 + nl]) : (short)0;
    o.z = (n < N) ? f2bf(T[(kl + 2) * 33 + nl]) : (short)0;
    o.w = (n < N) ? f2bf(T[(kl + 3) * 33 + nl]) : (short)0;
    *(short4_t*)&BT[(size_t)n * K + k0 + kl] = o;
  }
}

// ---------------------------------------------------------------------------
// Prep unit dispatcher: u=0 classify, 1..2048 x-cvt, then the 6 transposes.
// Units: 1 + 2048 + (1024+256+128+10112+7520+3256) = 24345.
// ---------------------------------------------------------------------------
__device__ __forceinline__ void prep_unit(const Params& p, int u, int tid,
                                          float* T, int* cnt_s) {
  if (u == 0) {
    if (tid == 0) { cnt_s[0] = 0; cnt_s[1] = 0; }
    __syncthreads();
    for (int r = tid; r < NROWS; r += 256) {
      const int yy = p.y[r];
      if (yy >= 20000) {
        const int s = atomicAdd(&cnt_s[1], 1);
        p.slot_of_row[r] = s; p.rows2[s] = r;
      } else if (yy >= 10000) {
        const int s = atomicAdd(&cnt_s[0], 1);
        p.slot_of_row[r] = s; p.rows1[s] = r;
      } else {
        p.slot_of_row[r] = -1;
      }
    }
    __syncthreads();
    if (tid == 0) {
      p.counts[0] = NROWS; p.counts[1] = cnt_s[0]; p.counts[2] = cnt_s[1];
    }
    return;
  }
  if (u <= 2048) {
    const int i = ((u - 1) * 256 + tid) * 4;
    short4_t o;
    o.x = f2bf(p.x[i + 0]); o.y = f2bf(p.x[i + 1]);
    o.z = f2bf(p.x[i + 2]); o.w = f2bf(p.x[i + 3]);
    *(short4_t*)&p.xb[i] = o;
    return;
  }
  int t = u - 2049;
  if (t < 1024)                transpose_tile(p.Wp0, p.WpT0, 1024, 1024, 1024, 32, t, tid, T);
  else if ((t -= 1024) < 256)  transpose_tile(p.Wp1, p.WpT1, 1024, 256, 256, 8, t, tid, T);
  else if ((t -= 256) < 128)   transpose_tile(p.Wp2, p.WpT2, 1024, 64, 128, 4, t, tid, T);
  else if ((t -= 128) < 10112) transpose_tile(p.Wl0, p.WlT0, 1024, 10000, 10112, 316, t, tid, T);
  else if ((t -= 10112) < 7520) transpose_tile(p.Wl1, p.WlT1, 256, 30000, 30080, 940, t, tid, T);
  else { t -= 7520;            transpose_tile(p.Wl2, p.WlT2, 64, 52000, 52096, 1628, t, tid, T); }
}

// ---------------------------------------------------------------------------
// Templated logit GEMM + sum-exp partials (r7 structure, 0 conflicts).
// ---------------------------------------------------------------------------
template <int K, int NCOLS, int NSPLIT, bool CS_SLOW>
__device__ __forceinline__ void logit_phase(
    const short* __restrict__ A, const short* __restrict__ BT,
    const float* __restrict__ bias, float* __restrict__ ps,
    short* As, short* Bs,
    int nrb, int csbase, int ncs, int lid, int step, int tid) {
  float* psL = (float*)As;              // alias: only touched after mainloop
  const int w = tid >> 6, lane = tid & 63;
  const int quad = lane >> 4, ln = lane & 15;
  const int wm = w >> 1, wn = w & 1;
  const int rsub = lane >> 3;
  const int kc = (lane & 7) ^ rsub;
  const int l7 = ln & 7;
  const int T = nrb * ncs;
  for (int t = lid; t < T; t += step) {
    const int rb = CS_SLOW ? (t % nrb) : (t / ncs);
    const int cs = csbase + (CS_SLOW ? (t / nrb) : (t % ncs));
    const int r0 = rb * 128, c0 = cs * 128;

    const short* aB[4]; const short* bB[4];
#pragma unroll
    for (int i = 0; i < 4; ++i) {
      aB[i] = A + (size_t)(r0 + w * 32 + i * 8 + rsub) * K + kc * 8;
      bB[i] = BT + (size_t)(c0 + w * 32 + i * 8 + rsub) * K + kc * 8;
    }
    f32x4 acc[4][4];
    const f32x4 zero = {0.f, 0.f, 0.f, 0.f};
#pragma unroll
    for (int i = 0; i < 4; ++i)
#pragma unroll
      for (int j = 0; j < 4; ++j) acc[i][j] = zero;

    __syncthreads();                    // psL (As) reads done before restage
    for (int kt = 0; kt < K; kt += 64) {
#pragma unroll
      for (int i = 0; i < 4; ++i) {
        const int row = w * 32 + i * 8;
        __builtin_amdgcn_global_load_lds(
            (const __attribute__((address_space(1))) void*)(aB[i] + kt),
            (__attribute__((address_space(3))) void*)(As + row * 64), 16, 0, 0);
        __builtin_amdgcn_global_load_lds(
            (const __attribute__((address_space(1))) void*)(bB[i] + kt),
            (__attribute__((address_space(3))) void*)(Bs + row * 64), 16, 0, 0);
      }
      __syncthreads();
#pragma unroll
      for (int ks = 0; ks < 2; ++ks) {
        const int kcs = ks * 4 + quad;
        short8 af[4], bfr[4];
#pragma unroll
        for (int mt = 0; mt < 4; ++mt) {
          const int row = wm * 64 + mt * 16 + ln;
          af[mt] = *(const short8*)(As + ((row * 8 + (kcs ^ l7)) << 3));
        }
#pragma unroll
        for (int nt = 0; nt < 4; ++nt) {
          const int rowb = wn * 64 + nt * 16 + ln;
          bfr[nt] = *(const short8*)(Bs + ((rowb * 8 + (kcs ^ l7)) << 3));
        }
#pragma unroll
        for (int mt = 0; mt < 4; ++mt)
#pragma unroll
          for (int nt = 0; nt < 4; ++nt)
            acc[mt][nt] = __builtin_amdgcn_mfma_f32_16x16x32_bf16(
                af[mt], bfr[nt], acc[mt][nt], 0, 0, 0);
      }
      __syncthreads();
    }

    float bv[4];
#pragma unroll
    for (int nt = 0; nt < 4; ++nt) {
      const int cg = c0 + wn * 64 + nt * 16 + ln;
      bv[nt] = (cg < NCOLS) ? bias[cg] : -1.0e30f;  // pad cols -> exp()=0
    }
#pragma unroll
    for (int mt = 0; mt < 4; ++mt)
#pragma unroll
      for (int r = 0; r < 4; ++r) {
        float s = 0.f;
#pragma unroll
        for (int nt = 0; nt < 4; ++nt)
          s += __expf(acc[mt][nt][r] + bv[nt]);
#pragma unroll
        for (int off = 1; off < 16; off <<= 1) s += __shfl_xor(s, off, 64);
        if (ln == 0) psL[wn * 128 + wm * 64 + mt * 16 + quad * 4 + r] = s;
      }
    __syncthreads();
    if (tid < 128)
      ps[(size_t)(r0 + tid) * NSPLIT + cs] = psL[tid] + psL[128 + tid];
  }
}

// Full merged logit pass for one block (head + tail1 + tail2, XCD-sliced).
__device__ __forceinline__ void logit_block(const Params& p, int bid, int tid,
                                            int step, short* As, short* Bs) {
  const int xcd = bid & 7;
  const int lid = bid >> 3;
  const int nrb1 = (p.counts[1] + 127) >> 7;
  const int nrb2 = (p.counts[2] + 127) >> 7;
  logit_phase<1024, 10000, 79, false>(p.P0b, p.WlT0, p.bl0, p.psh, As, Bs,
                                      16, xcd * 10, (xcd < 7) ? 10 : 9,
                                      lid, step, tid);
  logit_phase<256, 30000, 235, true>(p.P1c, p.WlT1, p.bl1, p.ps1, As, Bs,
                                     nrb1, xcd * 30, (xcd < 7) ? 30 : 25,
                                     lid, step, tid);
  logit_phase<64, 52000, 407, true>(p.P2c, p.WlT2, p.bl2, p.ps2, As, Bs,
                                    nrb2, xcd * 51, (xcd < 7) ? 51 : 50,
                                    lid, step, tid);
}

// ---------------------------------------------------------------------------
// Projection tile (inline row-gather for tails). C/D layout m89/m91.
// ---------------------------------------------------------------------------
__device__ __forceinline__ void proj_tile(const Params& p, int b, int tid,
                                          short* As, short* Bs) {
  const short* BT; short* C; int N, r0, c0, cnt;
  const int* rowlist = nullptr;
  if (b < 128) {
    BT = p.WpT0; C = p.P0b; N = 1024;
    c0 = (b & 7) * 128; r0 = (b >> 3) * 128; cnt = NROWS;
  } else if (b < 160) {
    b -= 128; BT = p.WpT1; C = p.P1c; N = 256;
    c0 = (b & 1) * 128; r0 = (b >> 1) * 128; rowlist = p.rows1; cnt = p.counts[1];
  } else {
    b -= 160; BT = p.WpT2; C = p.P2c; N = 64;
    c0 = 0; r0 = b * 128; rowlist = p.rows2; cnt = p.counts[2];
  }
  if (r0 >= cnt) return;                // function-return only; block continues

  const int w = tid >> 6, lane = tid & 63;
  const int quad = lane >> 4, ln = lane & 15;
  const int wm = w >> 1, wn = w & 1;
  const int rsub = lane >> 3;
  const int kc = (lane & 7) ^ rsub;
  const int l7 = ln & 7;
  const int K = 1024;

  const short* aB[4]; const short* bB[4];
#pragma unroll
  for (int i = 0; i < 4; ++i) {
    const int sl = r0 + w * 32 + i * 8 + rsub;
    const int ar = rowlist ? rowlist[sl < cnt ? sl : cnt - 1] : sl;
    aB[i] = p.xb + (size_t)ar * K + kc * 8;
    bB[i] = BT + (size_t)(c0 + w * 32 + i * 8 + rsub) * K + kc * 8;
  }

  f32x4 acc[4][4];
  const f32x4 zero = {0.f, 0.f, 0.f, 0.f};
#pragma unroll
  for (int i = 0; i < 4; ++i)
#pragma unroll
    for (int j = 0; j < 4; ++j) acc[i][j] = zero;
  __syncthreads();
  for (int kt = 0; kt < K; kt += 64) {
#pragma unroll
    for (int i = 0; i < 4; ++i) {
      const int row = w * 32 + i * 8;
      __builtin_amdgcn_global_load_lds(
          (const __attribute__((address_space(1))) void*)(aB[i] + kt),
          (__attribute__((address_space(3))) void*)(As + row * 64), 16, 0, 0);
      __builtin_amdgcn_global_load_lds(
          (const __attribute__((address_space(1))) void*)(bB[i] + kt),
          (__attribute__((address_space(3))) void*)(Bs + row * 64), 16, 0, 0);
    }
    __syncthreads();
#pragma unroll
    for (int ks = 0; ks < 2; ++ks) {
      const int kcs = ks * 4 + quad;
      short8 af[4], bfr[4];
#pragma unroll
      for (int mt = 0; mt < 4; ++mt) {
        const int row = wm * 64 + mt * 16 + ln;
        af[mt] = *(const short8*)(As + ((row * 8 + (kcs ^ l7)) << 3));
      }
#pragma unroll
      for (int nt = 0; nt < 4; ++nt) {
        const int rowb = wn * 64 + nt * 16 + ln;
        bfr[nt] = *(const short8*)(Bs + ((rowb * 8 + (kcs ^ l7)) << 3));
      }
#pragma unroll
      for (int mt = 0; mt < 4; ++mt)
#pragma unroll
        for (int nt = 0; nt < 4; ++nt)
          acc[mt][nt] = __builtin_amdgcn_mfma_f32_16x16x32_bf16(
              af[mt], bfr[nt], acc[mt][nt], 0, 0, 0);
    }
    __syncthreads();
  }
#pragma unroll
  for (int mt = 0; mt < 4; ++mt)
#pragma unroll
    for (int r = 0; r < 4; ++r) {
      const int grow = r0 + wm * 64 + mt * 16 + quad * 4 + r;
#pragma unroll
      for (int nt = 0; nt < 4; ++nt) {
        const int cg = c0 + wn * 64 + nt * 16 + ln;
        if (cg < N) C[(size_t)grow * N + cg] = f2bf(acc[mt][nt][r]);
      }
    }
}

// ---------------------------------------------------------------------------
// Finalize 4 rows (unit u = rows 4u..4u+3), one wave per row.
// ---------------------------------------------------------------------------
__device__ __forceinline__ void finalize_rows(const Params& p, int u, int tid) {
  const int lane = tid & 63;
  const int row = u * 4 + (tid >> 6);

  float a0 = 0.f, a1 = 0.f;
  for (int k = lane; k < HID; k += 64) {
    const float pv = bf2f(p.P0b[(size_t)row * HID + k]);
    a0 += pv * p.Wc[2 * k];
    a1 += pv * p.Wc[2 * k + 1];
  }
  a0 = wave_sum(a0);
  a1 = wave_sum(a1);
  const float cl0 = a0 + p.bc[0], cl1 = a1 + p.bc[1];

  float S = 0.f;
  for (int i = lane; i < 79; i += 64) S += p.psh[(size_t)row * 79 + i];
  S = wave_sum(S) + __expf(cl0) + __expf(cl1);
  const float lse = logf(S);

  const int yy = p.y[row];
  float nll;
  if (yy < 10000) {
    const short* pr = p.P0b + (size_t)row * 1024;
    const short* wr = p.WlT0 + (size_t)yy * 1024;
    float a = 0.f;
    for (int kk = lane * 4; kk < 1024; kk += 256) {
      const short4_t pv = *(const short4_t*)(pr + kk);
      const short4_t wv = *(const short4_t*)(wr + kk);
      a += bf2f(pv.x) * bf2f(wv.x) + bf2f(pv.y) * bf2f(wv.y)
         + bf2f(pv.z) * bf2f(wv.z) + bf2f(pv.w) * bf2f(wv.w);
    }
    a = wave_sum(a);
    nll = -((a + p.bl0[yy]) - lse);
  } else if (yy < 20000) {
    const int t = yy - 10000;
    const int slot = p.slot_of_row[row];
    float S1 = 0.f;
    for (int i = lane; i < 235; i += 64) S1 += p.ps1[(size_t)slot * 235 + i];
    S1 = wave_sum(S1);
    const short* pr = p.P1c + (size_t)slot * 256;
    const short* wr = p.WlT1 + (size_t)t * 256;
    const int kk = lane * 4;
    const short4_t pv = *(const short4_t*)(pr + kk);
    const short4_t wv = *(const short4_t*)(wr + kk);
    float a = bf2f(pv.x) * bf2f(wv.x) + bf2f(pv.y) * bf2f(wv.y)
            + bf2f(pv.z) * bf2f(wv.z) + bf2f(pv.w) * bf2f(wv.w);
    a = wave_sum(a);
    nll = -((cl1 - lse) + ((a + p.bl1[t]) - logf(S1)));
  } else {
    const int t = yy - 20000;
    const int slot = p.slot_of_row[row];
    float S2 = 0.f;
    for (int i = lane; i < 407; i += 64) S2 += p.ps2[(size_t)slot * 407 + i];
    S2 = wave_sum(S2);
    float a = 0.f;
    if (lane < 16) {
      const short* pr = p.P2c + (size_t)slot * 64;
      const short* wr = p.WlT2 + (size_t)t * 64;
      const int kk = lane * 4;
      const short4_t pv = *(const short4_t*)(pr + kk);
      const short4_t wv = *(const short4_t*)(wr + kk);
      a = bf2f(pv.x) * bf2f(wv.x) + bf2f(pv.y) * bf2f(wv.y)
        + bf2f(pv.z) * bf2f(wv.z) + bf2f(pv.w) * bf2f(wv.w);
    }
    a = wave_sum(a);
    nll = -((cl0 - lse) + ((a + p.bl2[t]) - logf(S2)));
  }
  if (lane == 0) p.out[row] = nll;
}

// ---------------------------------------------------------------------------
// MEGA: cooperative persistent kernel, grid = runtime-queried occupancy.
// P0 prep-all -> sync -> P1 proj(0..175) || Wl transposes -> (transposes done
// in P0 for simplicity of deps? no: P0 does everything EXCEPT nothing) ...
// Schedule: P0 = all prep units (classify/cvt/all 6 transposes);
//           P1 = proj; P2 = logit; P3 = finalize. P0 saturates the machine
// (24345 units), P1 is the only underfilled phase (176 blocks, ~25 us).
// ---------------------------------------------------------------------------
__global__ __launch_bounds__(256) void mega(Params p, int nb) {
  cg::grid_group grid = cg::this_grid();
  __shared__ short As[128 * 64];
  __shared__ short Bs[128 * 64];
  const int tid = threadIdx.x;
  const int bid = blockIdx.x;
  float* T = (float*)As;
  int* cnt_s = (int*)Bs;

  // ---- Phase 0: classify + x-cvt + ALL weight transposes ----
  for (int u = bid; u < 24345; u += nb) prep_unit(p, u, tid, T, cnt_s);
  __threadfence();
  grid.sync();

  // ---- Phase 1: projections (176 tiles) ----
  if (bid < 176) proj_tile(p, bid, tid, As, Bs);
  __threadfence();
  grid.sync();

  // ---- Phase 2: merged logit (XCD-sliced persistent) ----
  logit_block(p, bid, tid, nb >> 3, As, Bs);
  __threadfence();
  grid.sync();

  // ---- Phase 3: finalize ----
  for (int u = bid; u < 512; u += nb) finalize_rows(p, u, tid);
}

// ---------------------------------------------------------------------------
// Fallback ordinary kernels (r5/r7-verified structure).
// ---------------------------------------------------------------------------
__global__ __launch_bounds__(256) void fb_prep(Params p) {
  __shared__ float T[32 * 33];
  __shared__ int cnt_s[2];
  prep_unit(p, blockIdx.x, threadIdx.x, T, cnt_s);
}
__global__ __launch_bounds__(256) void fb_proj(Params p) {
  __shared__ short As[128 * 64];
  __shared__ short Bs[128 * 64];
  proj_tile(p, blockIdx.x, threadIdx.x, As, Bs);
}
__global__ __launch_bounds__(256) void fb_logit(Params p) {
  __shared__ short As[128 * 64];
  __shared__ short Bs[128 * 64];
  logit_block(p, blockIdx.x, threadIdx.x, 128, As, Bs);
}
__global__ __launch_bounds__(256) void fb_final(Params p) {
  finalize_rows(p, blockIdx.x, threadIdx.x);
}

// ---------------------------------------------------------------------------
extern "C" void kernel_launch(void* const* d_in, const int* in_sizes, int n_in,
                              void* d_out, int out_size, void* d_ws, size_t ws_size,
                              hipStream_t stream) {
  Params p;
  p.x   = (const float*)d_in[0];
  p.y   = (const int*)d_in[1];
  p.Wp0 = (const float*)d_in[2];
  p.Wp1 = (const float*)d_in[3];
  p.Wp2 = (const float*)d_in[4];
  p.Wl0 = (const float*)d_in[5];
  p.bl0 = (const float*)d_in[6];
  p.Wl1 = (const float*)d_in[7];
  p.bl1 = (const float*)d_in[8];
  p.Wl2 = (const float*)d_in[9];
  p.bl2 = (const float*)d_in[10];
  p.Wc  = (const float*)d_in[11];
  p.bc  = (const float*)d_in[12];
  p.out = (float*)d_out;

  float* fws = (float*)d_ws;
  p.psh = fws; fws += (size_t)NROWS * 79;
  p.ps1 = fws; fws += (size_t)NROWS * 235;
  p.ps2 = fws; fws += (size_t)NROWS * 407;
  int* iws = (int*)fws;
  p.counts      = iws; iws += 4;
  p.slot_of_row = iws; iws += NROWS;
  p.rows1       = iws; iws += NROWS;
  p.rows2       = iws; iws += NROWS;
  short* sp = (short*)iws;
  p.xb   = sp; sp += (size_t)NROWS * 1024;
  p.P0b  = sp; sp += (size_t)NROWS * 1024;
  p.P1c  = sp; sp += (size_t)NROWS * 256;
  p.P2c  = sp; sp += (size_t)NROWS * 64;
  p.WpT0 = sp; sp += (size_t)1024 * 1024;
  p.WpT1 = sp; sp += (size_t)256 * 1024;
  p.WpT2 = sp; sp += (size_t)128 * 1024;
  p.WlT0 = sp; sp += (size_t)10112 * 1024;
  p.WlT1 = sp; sp += (size_t)30080 * 256;
  p.WlT2 = sp; sp += (size_t)52096 * 64;

  // Runtime co-residency query (host-side, capture-safe, deterministic).
  int occ = 0;
  hipError_t qe = hipOccupancyMaxActiveBlocksPerMultiprocessor(&occ, mega, 256, 0);
  int nb = (qe == hipSuccess) ? occ * 256 : 0;
  if (nb > 1024) nb = 1024;
  nb &= ~7;

  if (nb >= 256) {
    void* args[] = {(void*)&p, (void*)&nb};
    hipLaunchCooperativeKernel((const void*)mega, dim3(nb), dim3(256),
                               args, 0, stream);
  } else {
    dim3 blk(256);
    fb_prep<<<dim3(24345), blk, 0, stream>>>(p);
    fb_proj<<<dim3(176), blk, 0, stream>>>(p);
    fb_logit<<<dim3(1024), blk, 0, stream>>>(p);
    fb_final<<<dim3(512), blk, 0, stream>>>(p);
  }
}